// Round 6
// baseline (537.498 us; speedup 1.0000x reference)
//
#include <hip/hip_runtime.h>
#include <math.h>

typedef unsigned short u16;
typedef __attribute__((ext_vector_type(8))) short bfrag;     // 8 bf16 = 4 VGPRs
typedef __attribute__((ext_vector_type(4))) float f32x4;     // MFMA acc
typedef __attribute__((ext_vector_type(4))) unsigned short us4;

#define B_SZ 32
#define L_SZ 3136
#define C_SZ 256
#define NHEADS 8
#define HID_SZ 1024
#define NW 49
#define NWIN 64
#define SHIFT 24
#define M_SZ (B_SZ * L_SZ)          // 100352
#define SCALEF 0.17677669529663687f // (256/8)^-0.5

__device__ __forceinline__ float bf2f(u16 u) {
  union { unsigned int i; float f; } v; v.i = ((unsigned)u) << 16; return v.f;
}
__device__ __forceinline__ u16 f2bf(float f) {
  union { unsigned int i; float f; } v; v.f = f;
  return (u16)((v.i + 0x7fffu + ((v.i >> 16) & 1u)) >> 16);
}
// async global->LDS, 16B per lane; LDS dest = wave-uniform base + lane*16
__device__ __forceinline__ void gload_lds16(const u16* g, u16* l) {
  __builtin_amdgcn_global_load_lds(
      (const __attribute__((address_space(1))) unsigned int*)g,
      (__attribute__((address_space(3))) unsigned int*)l, 16, 0, 0);
}

// ---------------- weight transpose: (K,N) f32 -> (N,K) bf16 row-major --------
__global__ void transpose_kernel(const float* __restrict__ in, u16* __restrict__ out,
                                 int K, int N) {
  const int idx = blockIdx.x * 256 + threadIdx.x;
  if (idx >= K * N) return;
  const int n = idx / K;
  const int k = idx - n * K;
  out[idx] = f2bf(in[(size_t)k * N + n]);
}

// ---------------- relative-position bias gather: (64,8,49,49) f32 ------------
__global__ void bias_kernel(const float* __restrict__ tab, const int* __restrict__ rel,
                            float* __restrict__ bm) {
  const int idx = blockIdx.x * 256 + threadIdx.x;
  const int tot = NWIN * NHEADS * NW * NW;
  if (idx >= tot) return;
  const int w = idx / (NHEADS * NW * NW);
  const int r = idx - w * (NHEADS * NW * NW);
  const int h = r / (NW * NW);
  const int ij = r - h * (NW * NW);
  bm[idx] = tab[(size_t)rel[w * NW * NW + ij] * NHEADS + h];
}

// ============ FUSED: LN1 + roll + qkv-proj + windowed attention ==============
// One block per window (2048 blocks). LDS: h 32KB + 4 waves x 12KB = 80KB
// -> 2 blocks/CU. Each wave handles 2 heads; Q/K/V generated by MFMA into
// wave-private XOR-swizzled LDS; V stored transposed so PV B-frags are
// contiguous ds_read_b128. P overlays Q+K. Pad rows 49..63 zero-filled.
__global__ __launch_bounds__(256, 2) void qkvattn_kernel(
    const float* __restrict__ x, const float* __restrict__ n1w,
    const float* __restrict__ n1b, const u16* __restrict__ qkvwT,
    const float* __restrict__ qkvb, const float* __restrict__ bm,
    u16* __restrict__ out) {
  __shared__ u16 hs[64 * 256];           // chunk(8)-XOR (r&7)
  __shared__ u16 wscr[4][3 * 64 * 32];   // per wave: q | k | vT
  const int widx = blockIdx.x;
  const int b = widx >> 6;
  const int w = widx & 63;
  const int wv = threadIdx.x >> 6;
  const int lane = threadIdx.x & 63;
  const int lr = lane & 15;
  const int lg = lane >> 4;
  const f32x4 fzero = {0.f, 0.f, 0.f, 0.f};

  // ---- A: LN1 + roll-gather into h LDS (bf16, swizzled) ----
  float wv4[4], bv4[4];
#pragma unroll
  for (int j = 0; j < 4; ++j) { wv4[j] = n1w[lane * 4 + j]; bv4[j] = n1b[lane * 4 + j]; }
  for (int r = wv; r < 64; r += 4) {
    u16* hp = hs + r * 256 + (((lane >> 1) ^ (r & 7)) << 3) + ((lane & 1) << 2);
    if (r < NW) {
      int l = w * NW + r - SHIFT;
      if (l < 0) l += L_SZ;
      const float4 u = *((const float4*)x + ((size_t)b * L_SZ + l) * 64 + lane);
      float s = u.x + u.y + u.z + u.w;
      float sq = u.x * u.x + u.y * u.y + u.z * u.z + u.w * u.w;
#pragma unroll
      for (int d = 1; d < 64; d <<= 1) { s += __shfl_xor(s, d); sq += __shfl_xor(sq, d); }
      const float mu = s * (1.0f / C_SZ);
      const float rs = rsqrtf(sq * (1.0f / C_SZ) - mu * mu + 1e-5f);
      const float vv[4] = {u.x, u.y, u.z, u.w};
      us4 ov;
#pragma unroll
      for (int j = 0; j < 4; ++j) ov[j] = f2bf((vv[j] - mu) * rs * wv4[j] + bv4[j]);
      *(us4*)hp = ov;
    } else {
      us4 z = {0, 0, 0, 0};
      *(us4*)hp = z;
    }
  }
  __syncthreads();

  u16* q   = wscr[wv];            // [64][32] chunk-XOR (r&3)
  u16* kk_ = q + 64 * 32;         // [64][32] chunk-XOR (r&3)
  u16* vT  = q + 2 * 64 * 32;     // [32][64] chunk-XOR (c&7), vT[dcol][kk]
  u16* P   = q;                   // [64][64] chunk-XOR (r&7), overlays q+k

  for (int rep = 0; rep < 2; ++rep) {
    const int hh = wv * 2 + rep;
    // ---- B1: generate Q, K, V via MFMA (h in LDS x weights in L2) ----
#pragma unroll
    for (int mat = 0; mat < 3; ++mat) {
      f32x4 a4[4][2];
#pragma unroll
      for (int m = 0; m < 4; ++m) { a4[m][0] = fzero; a4[m][1] = fzero; }
      const u16* wbase = qkvwT + (size_t)(mat * 256 + hh * 32) * 256;
#pragma unroll
      for (int kt = 0; kt < 8; ++kt) {
        bfrag bf[2], af[4];
#pragma unroll
        for (int n = 0; n < 2; ++n)
          bf[n] = *(const bfrag*)(wbase + (size_t)(n * 16 + lr) * 256 + kt * 32 + lg * 8);
#pragma unroll
        for (int m = 0; m < 4; ++m) {
          const int r = m * 16 + lr;
          af[m] = *(const bfrag*)(hs + r * 256 + (((kt * 4 + lg) ^ (r & 7)) << 3));
        }
#pragma unroll
        for (int m = 0; m < 4; ++m)
#pragma unroll
          for (int n = 0; n < 2; ++n)
            a4[m][n] = __builtin_amdgcn_mfma_f32_16x16x32_bf16(af[m], bf[n],
                                                               a4[m][n], 0, 0, 0);
      }
      float bb[2];
#pragma unroll
      for (int n = 0; n < 2; ++n) bb[n] = qkvb[mat * 256 + hh * 32 + n * 16 + lr];
      u16* dst = (mat == 0) ? q : (mat == 1) ? kk_ : vT;
#pragma unroll
      for (int m = 0; m < 4; ++m)
#pragma unroll
        for (int n = 0; n < 2; ++n)
#pragma unroll
          for (int i = 0; i < 4; ++i) {
            const int r2 = m * 16 + lg * 4 + i;
            const int c = n * 16 + lr;
            const u16 val = f2bf(a4[m][n][i] + bb[n]);
            if (mat < 2) dst[r2 * 32 + (((c >> 3) ^ (r2 & 3)) << 3) + (c & 7)] = val;
            else         dst[c * 64 + (((r2 >> 3) ^ (c & 7)) << 3) + (r2 & 7)] = val;
          }
    }
    // ---- B2: S = Q K^T (head_dim 32 = one k-step) ----
    bfrag qf[4], kf[4];
#pragma unroll
    for (int m = 0; m < 4; ++m) {
      const int r = m * 16 + lr;
      qf[m] = *(const bfrag*)(q + r * 32 + ((lg ^ (r & 3)) << 3));
      kf[m] = *(const bfrag*)(kk_ + r * 32 + ((lg ^ (r & 3)) << 3));
    }
    f32x4 S[4][4];
#pragma unroll
    for (int m = 0; m < 4; ++m)
#pragma unroll
      for (int n = 0; n < 4; ++n)
        S[m][n] = __builtin_amdgcn_mfma_f32_16x16x32_bf16(qf[m], kf[n], fzero, 0, 0, 0);

    // ---- B3: softmax (+bias), P -> LDS (overlays q,k) ----
    const float* bh = bm + (size_t)(w * NHEADS + hh) * (NW * NW);
#pragma unroll
    for (int m = 0; m < 4; ++m) {
#pragma unroll
      for (int i = 0; i < 4; ++i) {
        const int row = m * 16 + lg * 4 + i;
        const int brow = row > NW - 1 ? NW - 1 : row;
        float vals[4];
#pragma unroll
        for (int n = 0; n < 4; ++n) {
          const int c = n * 16 + lr;
          vals[n] = (c < NW) ? (S[m][n][i] * SCALEF + bh[brow * NW + c]) : -1e30f;
        }
        float mx = fmaxf(fmaxf(vals[0], vals[1]), fmaxf(vals[2], vals[3]));
#pragma unroll
        for (int d = 1; d < 16; d <<= 1) mx = fmaxf(mx, __shfl_xor(mx, d));
        float sum = 0.f;
#pragma unroll
        for (int n = 0; n < 4; ++n) { vals[n] = __expf(vals[n] - mx); sum += vals[n]; }
#pragma unroll
        for (int d = 1; d < 16; d <<= 1) sum += __shfl_xor(sum, d);
        const float inv = 1.0f / sum;
#pragma unroll
        for (int n = 0; n < 4; ++n) {
          const int c = n * 16 + lr;
          P[row * 64 + (((c >> 3) ^ (row & 7)) << 3) + (c & 7)] = f2bf(vals[n] * inv);
        }
      }
    }
    // ---- B4: O = P V (vT gives contiguous B-frags) ----
    f32x4 o[4][2];
#pragma unroll
    for (int m = 0; m < 4; ++m) { o[m][0] = fzero; o[m][1] = fzero; }
#pragma unroll
    for (int s2 = 0; s2 < 2; ++s2) {
      bfrag pf[4], vf[2];
#pragma unroll
      for (int m = 0; m < 4; ++m) {
        const int r = m * 16 + lr;
        pf[m] = *(const bfrag*)(P + r * 64 + (((s2 * 4 + lg) ^ (r & 7)) << 3));
      }
#pragma unroll
      for (int n = 0; n < 2; ++n) {
        const int dc = n * 16 + lr;
        vf[n] = *(const bfrag*)(vT + dc * 64 + (((s2 * 4 + lg) ^ (dc & 7)) << 3));
      }
#pragma unroll
      for (int m = 0; m < 4; ++m)
#pragma unroll
        for (int n = 0; n < 2; ++n)
          o[m][n] = __builtin_amdgcn_mfma_f32_16x16x32_bf16(pf[m], vf[n],
                                                            o[m][n], 0, 0, 0);
    }
    // ---- B5: store attn out (rolled window space) ----
#pragma unroll
    for (int m = 0; m < 4; ++m)
#pragma unroll
      for (int i = 0; i < 4; ++i) {
        const int row = m * 16 + lg * 4 + i;
        if (row < NW) {
#pragma unroll
          for (int n = 0; n < 2; ++n)
            out[((size_t)widx * NW + row) * C_SZ + hh * 32 + n * 16 + lr] =
                f2bf(o[m][n][i]);
        }
      }
  }
}

// ---------------- LayerNorm2 (bf16 in), no roll; 4 rows/wave -----------------
__global__ __launch_bounds__(256) void ln2_kernel(
    const u16* __restrict__ x, const float* __restrict__ w,
    const float* __restrict__ b, u16* __restrict__ out) {
  const int wv = threadIdx.x >> 6;
  const int lane = threadIdx.x & 63;
  const int row0 = blockIdx.x * 16 + wv * 4;
  us4 u[4];
#pragma unroll
  for (int r = 0; r < 4; ++r)
    u[r] = *(const us4*)(x + (size_t)(row0 + r) * C_SZ + lane * 4);
  float v[4][4], s[4], sq[4];
#pragma unroll
  for (int r = 0; r < 4; ++r) {
    s[r] = 0.f; sq[r] = 0.f;
#pragma unroll
    for (int j = 0; j < 4; ++j) {
      v[r][j] = bf2f(u[r][j]); s[r] += v[r][j]; sq[r] += v[r][j] * v[r][j];
    }
  }
#pragma unroll
  for (int d = 1; d < 64; d <<= 1)
#pragma unroll
    for (int r = 0; r < 4; ++r) {
      s[r] += __shfl_xor(s[r], d); sq[r] += __shfl_xor(sq[r], d);
    }
  float wv4[4], bv4[4];
#pragma unroll
  for (int j = 0; j < 4; ++j) { wv4[j] = w[lane * 4 + j]; bv4[j] = b[lane * 4 + j]; }
#pragma unroll
  for (int r = 0; r < 4; ++r) {
    const float mu = s[r] * (1.0f / C_SZ);
    const float rs = rsqrtf(sq[r] * (1.0f / C_SZ) - mu * mu + 1e-5f);
    us4 ov;
#pragma unroll
    for (int j = 0; j < 4; ++j) ov[j] = f2bf((v[r][j] - mu) * rs * wv4[j] + bv4[j]);
    *(us4*)(out + (size_t)(row0 + r) * C_SZ + lane * 4) = ov;
  }
}

// ---------------- tiled MFMA GEMM: C = A(MxK) * Bt(NxK)^T + bias -------------
// Staging: global_load_lds 16B/lane, LDS linear, XOR-swizzle folded into the
// per-lane GLOBAL source address (inverse-swz source + swz read).
// MODE 1: proj (un-roll + x residual -> bf16)
// MODE 2: exact GELU, bf16           MODE 3: + bf16 residual -> f32 d_out
#define BM 128
#define BN 128
#define BKT 64

template <int MODE>
__global__ __launch_bounds__(256, 2) void gemm_kernel(
    const u16* __restrict__ A, const u16* __restrict__ Bt,
    const float* __restrict__ bias, int N, int K, void* __restrict__ Cout,
    const float* __restrict__ resx, const u16* __restrict__ resb2) {
  __shared__ u16 Als[BM * BKT];
  __shared__ u16 Bls[BN * BKT];
  const int tid = threadIdx.x;
  const int lane = tid & 63;
  const int lr = lane & 15;
  const int lg = lane >> 4;
  const int m0 = blockIdx.y * BM;
  const int n0 = blockIdx.x * BN;
  const int wid = tid >> 6;
  const int wm = (wid >> 1) * 64;
  const int wn = (wid & 1) * 64;

  const int grow = lane >> 3;              // row within 8-row group
  const int gch = (lane & 7) ^ grow;       // pre-swizzled source k-chunk

  const f32x4 fzero = {0.f, 0.f, 0.f, 0.f};
  f32x4 acc[4][4];
#pragma unroll
  for (int i = 0; i < 4; ++i)
#pragma unroll
    for (int j = 0; j < 4; ++j) acc[i][j] = fzero;

  const u16* Agl = A + (size_t)m0 * K + gch * 8;
  const u16* Bgl = Bt + (size_t)n0 * K + gch * 8;

  for (int k0 = 0; k0 < K; k0 += BKT) {
#pragma unroll
    for (int g = 0; g < 4; ++g) {
      const int rbase = wid * 32 + g * 8;
      gload_lds16(Agl + (size_t)(rbase + grow) * K + k0, Als + rbase * 64);
      gload_lds16(Bgl + (size_t)(rbase + grow) * K + k0, Bls + rbase * 64);
    }
    __syncthreads();
#pragma unroll
    for (int s = 0; s < 2; ++s) {
      const int kg = s * 4 + lg;
      bfrag af[4], bfv[4];
#pragma unroll
      for (int m = 0; m < 4; ++m) {
        const int r = wm + m * 16 + lr;
        af[m] = *(const bfrag*)(Als + r * 64 + ((kg ^ (r & 7)) * 8));
      }
#pragma unroll
      for (int n = 0; n < 4; ++n) {
        const int r = wn + n * 16 + lr;
        bfv[n] = *(const bfrag*)(Bls + r * 64 + ((kg ^ (r & 7)) * 8));
      }
#pragma unroll
      for (int m = 0; m < 4; ++m)
#pragma unroll
        for (int n = 0; n < 4; ++n)
          acc[m][n] = __builtin_amdgcn_mfma_f32_16x16x32_bf16(af[m], bfv[n],
                                                              acc[m][n], 0, 0, 0);
    }
    __syncthreads();
  }

  float bv4[4];
#pragma unroll
  for (int n = 0; n < 4; ++n) bv4[n] = bias[n0 + wn + n * 16 + lr];

#pragma unroll
  for (int m = 0; m < 4; ++m) {
#pragma unroll
    for (int i = 0; i < 4; ++i) {
      const int row = m0 + wm + m * 16 + lg * 4 + i;
      if (MODE == 1) {
        const int bb = row / L_SZ;
        int l2 = row - bb * L_SZ - SHIFT;
        if (l2 < 0) l2 += L_SZ;
        const size_t orow = (size_t)bb * L_SZ + l2;
#pragma unroll
        for (int n = 0; n < 4; ++n) {
          const int col = n0 + wn + n * 16 + lr;
          ((u16*)Cout)[orow * N + col] =
              f2bf(resx[orow * N + col] + acc[m][n][i] + bv4[n]);
        }
      } else {
#pragma unroll
        for (int n = 0; n < 4; ++n) {
          const int col = n0 + wn + n * 16 + lr;
          float v = acc[m][n][i] + bv4[n];
          if (MODE == 2) v = 0.5f * v * (1.0f + erff(v * 0.70710678f));
          if (MODE == 3) {
            v += bf2f(resb2[(size_t)row * N + col]);
            ((float*)Cout)[(size_t)row * N + col] = v;   // f32 final output
          } else {
            ((u16*)Cout)[(size_t)row * N + col] = f2bf(v);
          }
        }
      }
    }
  }
}

// -----------------------------------------------------------------------------
extern "C" void kernel_launch(void* const* d_in, const int* in_sizes, int n_in,
                              void* d_out, int out_size, void* d_ws, size_t ws_size,
                              hipStream_t stream) {
  (void)in_sizes; (void)n_in; (void)out_size;
  const float* x     = (const float*)d_in[0];
  const float* qkvw  = (const float*)d_in[1];
  const float* qkvb  = (const float*)d_in[2];
  const float* projw = (const float*)d_in[3];
  const float* projb = (const float*)d_in[4];
  const float* btab  = (const float*)d_in[5];
  const float* n1w   = (const float*)d_in[6];
  const float* n1b   = (const float*)d_in[7];
  const float* n2w   = (const float*)d_in[8];
  const float* n2b   = (const float*)d_in[9];
  const float* fc1w  = (const float*)d_in[10];
  const float* fc1b  = (const float*)d_in[11];
  const float* fc2w  = (const float*)d_in[12];
  const float* fc2b  = (const float*)d_in[13];
  const int* rel     = (const int*)d_in[14];

  char* ws = (char*)d_ws;
  size_t off = 0;
  auto alloc = [&](size_t bytes) -> char* {
    char* p = ws + off; off += (bytes + 255) & ~(size_t)255; return p;
  };
  u16* qkvwT   = (u16*)alloc((size_t)768 * 256 * 2);
  u16* projwT  = (u16*)alloc((size_t)256 * 256 * 2);
  u16* fc1wT   = (u16*)alloc((size_t)1024 * 256 * 2);
  u16* fc2wT   = (u16*)alloc((size_t)256 * 1024 * 2);
  float* biasm = (float*)alloc((size_t)NWIN * NHEADS * NW * NW * 4);
  u16* bufh    = (u16*)alloc((size_t)M_SZ * C_SZ * 2);   // attn-out / h2
  u16* x2b     = (u16*)alloc((size_t)M_SZ * C_SZ * 2);   // bf16 residual x2

  // dynamic chunking for the MLP scratch (fc1 activations)
  const size_t full_scr = (size_t)M_SZ * HID_SZ * 2;
  const int nch = (ws_size >= off + full_scr + 256) ? 1 : 4;
  const int mch = M_SZ / nch;                 // rows per chunk
  u16* scratch2 = (u16*)alloc((size_t)mch * HID_SZ * 2);

  transpose_kernel<<<(256 * 768 + 255) / 256, 256, 0, stream>>>(qkvw, qkvwT, 256, 768);
  transpose_kernel<<<(256 * 256 + 255) / 256, 256, 0, stream>>>(projw, projwT, 256, 256);
  transpose_kernel<<<(256 * 1024 + 255) / 256, 256, 0, stream>>>(fc1w, fc1wT, 256, 1024);
  transpose_kernel<<<(1024 * 256 + 255) / 256, 256, 0, stream>>>(fc2w, fc2wT, 1024, 256);
  bias_kernel<<<(NWIN * NHEADS * NW * NW + 255) / 256, 256, 0, stream>>>(btab, rel, biasm);

  // fused LN1 + roll + qkv + attention -> bufh (rolled window space)
  qkvattn_kernel<<<B_SZ * NWIN, 256, 0, stream>>>(x, n1w, n1b, qkvwT, qkvb,
                                                  biasm, bufh);

  // proj + un-roll + x residual -> bf16 x2 (full M: needs absolute rows)
  gemm_kernel<1><<<dim3(256 / BN, M_SZ / BM), 256, 0, stream>>>(
      bufh, projwT, projb, 256, 256, x2b, x, nullptr);

  // MLP per chunk; final fc2 writes f32 to d_out
  for (int q = 0; q < nch; ++q) {
    const size_t roff = (size_t)q * mch;
    ln2_kernel<<<mch / 16, 256, 0, stream>>>(x2b + roff * C_SZ, n2w, n2b,
                                             bufh + roff * C_SZ);
    gemm_kernel<2><<<dim3(1024 / BN, mch / BM), 256, 0, stream>>>(
        bufh + roff * C_SZ, fc1wT, fc1b, 1024, 256, scratch2, nullptr, nullptr);
    gemm_kernel<3><<<dim3(256 / BN, mch / BM), 256, 0, stream>>>(
        scratch2, fc2wT, fc2b, 256, 1024, (float*)d_out + roff * C_SZ,
        nullptr, x2b + roff * C_SZ);
  }
}